// Round 1
// 110.696 us; speedup vs baseline: 1.1390x; 1.1390x over previous
//
#include <hip/hip_runtime.h>

#define NBINS 128
#define NB2   (NBINS * NBINS)
#define TPB   1024            // 16 waves = 4 teams x 4 quadrant-waves
#define NBLK  256             // 1 block/CU
#define KC    32              // points per chunk (halved: tiles double-buffer in LDS)
#define NTEAM 4
#define ROWB  (KC * 2)        // tile row bytes (bf16)

typedef __attribute__((ext_vector_type(8)))  short short8;
typedef __attribute__((ext_vector_type(16))) float f32x16;

// native 2^x (v_exp_f32); inputs here are <= ~127 in magnitude and finite
__device__ __forceinline__ float exp2_fast(float x) {
#if defined(__has_builtin)
#if __has_builtin(__builtin_amdgcn_exp2f)
    return __builtin_amdgcn_exp2f(x);
#else
    return exp2f(x);
#endif
#else
    return exp2f(x);
#endif
}

// pack two fp32 -> two bf16 (round-half-up) in one v_perm: [bf16(b) : bf16(a)]
__device__ __forceinline__ unsigned pk_bf16(float a, float b) {
    const unsigned ar = __float_as_uint(a) + 0x8000u;
    const unsigned br = __float_as_uint(b) + 0x8000u;
    return __builtin_amdgcn_perm(br, ar, 0x07060302u);
}

// C = -0.5 * log2(e): weight(d) = exp(-0.5 d^2) = exp2(WC d^2)
#define WC (-0.72134752044448170f)
// ratio-of-ratios: w(m+1)/w(m) shrinks by 2^(2*WC) = e^-1 per step
#define E1 (0.36787944117144233f)

// LDS: double-buffered per-team A/B bf16 tiles (128 KB) + u/v staging (2 KB);
// the 64 KB merge buffer aliases the tiles (used only after the main loop).
union __align__(16) ShMem {
    struct {
        unsigned short tiles[2][NTEAM][2][NBINS][KC]; // [buf][team][dim][tap][pt]
        float uv[2][NTEAM][2][KC];                    // [buf][team][dim][pt]
    } s;
    float hist[NB2];
};

// Kernel 1: hist = kx^T * ky as 128x128xK bf16 MFMA GEMM.
// Weight generation now uses the Gaussian ratio recurrence (2 fmul/tap instead
// of 1 exp2/tap) into shared LDS tiles (each weight computed ONCE per team,
// not twice per quadrant-wave-pair). 8 tap-bands of 16, each swept outward
// from its center c: w(c)=exp2(WC d^2), up-ratio r=exp2(WC(1-2d)),
// down-ratio q=exp2(WC(1+2d)), both decaying by E1 per step -> ratios <= ~1,
// no overflow; bands with |d|>13 underflow to exact 0 where true w ~ 0.
// clamp(d,+-88) keeps the ratio exp2 finite for far/pad points (else 0*inf=NaN).
// Tiles are XOR-swizzled ((m&3)<<4) so strided b128 fragment reads are 2-way
// (free); synchronized pair-writes are conflict-free (lane = point column).
__global__ __launch_bounds__(TPB, 4) void kde_mfma_kernel(
    const float* __restrict__ x,
    const float* __restrict__ ex,
    const float* __restrict__ ey,
    float* __restrict__ out,
    int n, int nchunks)
{
    __shared__ ShMem sm;

    const int tid  = (int)threadIdx.x;
    const int lane = tid & 63;
    const int half = lane >> 5;          // k-half of a 16-k step
    const int l31  = lane & 31;
    const int w4   = (tid >> 6) & 3;     // wave within team
    const int team = tid >> 8;           // 0..3
    const int rowblk = (w4 >> 1) * 64;
    const int colblk = (w4 & 1) * 64;

    const float lox = ex[0], loy = ey[0];
    const float ibx = 1.0f / (ex[1] - ex[0]);
    const float iby = 1.0f / (ey[1] - ey[0]);

    // weight-gen role: team-local thread -> (point-pair, dim, 16-tap band)
    const int tt     = tid & 255;
    const int pI     = tt & 15;          // point pair (points 2pI, 2pI+1)
    const int dimi   = (tt >> 4) & 1;    // 0 = x/A-tile, 1 = y/B-tile
    const int eighth = tt >> 5;          // tap band [16e, 16e+16)
    const float cc   = (float)(eighth * 16 + 8);

    f32x16 acc[2][2];
    #pragma unroll
    for (int a = 0; a < 2; ++a)
        #pragma unroll
        for (int c = 0; c < 2; ++c)
            #pragma unroll
            for (int r = 0; r < 16; ++r) acc[a][c][r] = 0.f;

    const int niter = (nchunks + NBLK * NTEAM - 1) / (NBLK * NTEAM);

    // stage u/v for iteration jt into buffer jt&1 (threads 0..127)
    auto stage = [&](int jt) {
        if (tid < NTEAM * KC && jt < niter) {
            const int tm = tid >> 5, idx = tid & 31;
            const int g  = (int)blockIdx.x * NTEAM + tm + jt * (NBLK * NTEAM);
            if (g < nchunks) {
                const int p = g * KC + idx;
                float uu = 1e9f, vv = 1e9f;   // pad: clamp in gen -> zero weights
                if (p < n) {
                    const float2 xy = *(const float2*)(x + (size_t)p * 6);
                    uu = (xy.x - lox) * ibx - 0.5f;
                    vv = (xy.y - loy) * iby - 0.5f;
                }
                sm.s.uv[jt & 1][tm][0][idx] = uu;
                sm.s.uv[jt & 1][tm][1][idx] = vv;
            }
        }
    };

    // generate both tiles for iteration jt into tiles[jt&1]
    auto gen = [&](int jt) {
        const int g = (int)blockIdx.x * NTEAM + team + jt * (NBLK * NTEAM);
        if (g >= nchunks) return;
        const int bb = jt & 1;
        const float* uvp = sm.s.uv[bb][team][dimi];
        const float u0 = uvp[2 * pI], u1 = uvp[2 * pI + 1];
        const float d0 = fminf(fmaxf(u0 - cc, -88.f), 88.f);
        const float d1 = fminf(fmaxf(u1 - cc, -88.f), 88.f);
        const float w0 = exp2_fast((WC * d0) * d0);
        const float w1 = exp2_fast((WC * d1) * d1);
        float r0 = exp2_fast(fmaf(-2.f * WC, d0, WC));
        float r1 = exp2_fast(fmaf(-2.f * WC, d1, WC));
        float q0 = exp2_fast(fmaf( 2.f * WC, d0, WC));
        float q1 = exp2_fast(fmaf( 2.f * WC, d1, WC));
        char* tb0 = (char*)&sm.s.tiles[bb][team][dimi][0][0]
                  + (eighth * 16 + 8) * ROWB;          // row c base (c%4 == 0)
        const int o0 = pI << 2;                         // swizzled column offsets
        const int os[4] = { o0, o0 ^ 16, o0 ^ 32, o0 ^ 48 };
        float a0 = w0, a1 = w1;
        #pragma unroll
        for (int j = 0; j < 8; ++j) {                   // up: m = c..c+7
            *(unsigned*)(tb0 + j * ROWB + os[j & 3]) = pk_bf16(a0, a1);
            a0 *= r0; r0 *= E1;
            a1 *= r1; r1 *= E1;
        }
        a0 = w0; a1 = w1;
        #pragma unroll
        for (int j = 1; j <= 8; ++j) {                  // down: m = c-1..c-8
            a0 *= q0; a1 *= q1;
            *(unsigned*)(tb0 - j * ROWB + os[(4 - j) & 3]) = pk_bf16(a0, a1);
            q0 *= E1; q1 *= E1;
        }
    };

    // MFMA for iteration it from tiles[it&1]
    auto domfma = [&](int it) {
        const int g = (int)blockIdx.x * NTEAM + team + it * (NBLK * NTEAM);
        if (g >= nchunks) return;
        const int bb = it & 1;
        const char* Ab = (const char*)&sm.s.tiles[bb][team][0][0][0];
        const char* Bb = (const char*)&sm.s.tiles[bb][team][1][0][0];
        const int ra = rowblk + l31, ca = colblk + l31;
        const int swa = (ra & 3) << 4, swb = (ca & 3) << 4; // (ra+32)&3 == ra&3
        #pragma unroll
        for (int s4 = 0; s4 < 2; ++s4) {
            const int kb2 = s4 * 32 + half * 16;            // byte offset in row
            const short8 a0 = *(const short8*)(Ab + ra * ROWB        + (kb2 ^ swa));
            const short8 a1 = *(const short8*)(Ab + (ra + 32) * ROWB + (kb2 ^ swa));
            const short8 b0 = *(const short8*)(Bb + ca * ROWB        + (kb2 ^ swb));
            const short8 b1 = *(const short8*)(Bb + (ca + 32) * ROWB + (kb2 ^ swb));
            acc[0][0] = __builtin_amdgcn_mfma_f32_32x32x16_bf16(a0, b0, acc[0][0], 0, 0, 0);
            acc[0][1] = __builtin_amdgcn_mfma_f32_32x32x16_bf16(a0, b1, acc[0][1], 0, 0, 0);
            acc[1][0] = __builtin_amdgcn_mfma_f32_32x32x16_bf16(a1, b0, acc[1][0], 0, 0, 0);
            acc[1][1] = __builtin_amdgcn_mfma_f32_32x32x16_bf16(a1, b1, acc[1][1], 0, 0, 0);
        }
    };

    // software pipeline: one barrier per iteration; gen(it+1) and stage(it+2)
    // overlap domfma(it) on disjoint buffers (VALU vs LDS/MFMA pipes).
    stage(0);
    __syncthreads();
    stage(1);
    gen(0);
    __syncthreads();
    for (int it = 0; it < niter; ++it) {
        stage(it + 2);
        domfma(it);
        gen(it + 1);
        __syncthreads();
    }
    // loop ends with a barrier: safe to alias tiles with hist now.

    // merge teams into LDS hist: 4 barrier-ordered passes of plain ds ops.
    // C/D layout (verified R6): row=(r&3)+8*(r>>2)+4*half, col=l31 per tile.
    for (int tm = 0; tm < NTEAM; ++tm) {
        if (team == tm) {
            #pragma unroll
            for (int rb = 0; rb < 2; ++rb)
                #pragma unroll
                for (int tj = 0; tj < 2; ++tj)
                    #pragma unroll
                    for (int r = 0; r < 16; ++r) {
                        const int row = rowblk + rb * 32 + (r & 3) + 8 * (r >> 2) + 4 * half;
                        const int col = colblk + tj * 32 + l31;
                        const int a = row * NBINS + col;
                        const float v = acc[rb][tj][r];
                        if (tm == 0) sm.hist[a] = v;
                        else         sm.hist[a] += v;
                    }
        }
        __syncthreads();
    }

    // device-scope atomic merge into out (zeroed host-side)
    for (int i = tid; i < NB2; i += TPB)
        unsafeAtomicAdd(&out[i], sm.hist[i]);
}

// Kernel 2 (fused finalize): single block; total-reduce in registers,
// normalize in place.
__global__ __launch_bounds__(TPB) void kde_final_kernel(
    float* __restrict__ out,
    const float* __restrict__ ex,
    const float* __restrict__ ey)
{
    __shared__ float red[TPB / 64];
    __shared__ float sinv;
    const int tid = (int)threadIdx.x;

    float4 v[4];
    float s = 0.f;
    #pragma unroll
    for (int i = 0; i < 4; ++i) {
        v[i] = ((const float4*)out)[tid + i * TPB];
        s += v[i].x + v[i].y + v[i].z + v[i].w;
    }
    #pragma unroll
    for (int off = 32; off > 0; off >>= 1) s += __shfl_down(s, off, 64);
    if ((tid & 63) == 0) red[tid >> 6] = s;
    __syncthreads();
    if (tid == 0) {
        float t = 0.f;
        #pragma unroll
        for (int i = 0; i < TPB / 64; ++i) t += red[i];
        sinv = 1.0f / (t * (ex[1] - ex[0]) * (ey[1] - ey[0]));
    }
    __syncthreads();
    const float inv = sinv;
    #pragma unroll
    for (int i = 0; i < 4; ++i) {
        float4 o = v[i];
        o.x *= inv; o.y *= inv; o.z *= inv; o.w *= inv;
        ((float4*)out)[tid + i * TPB] = o;
    }
}

extern "C" void kernel_launch(void* const* d_in, const int* in_sizes, int n_in,
                              void* d_out, int out_size, void* d_ws, size_t ws_size,
                              hipStream_t stream)
{
    const float* x  = (const float*)d_in[0];
    const float* ex = (const float*)d_in[1];
    const float* ey = (const float*)d_in[2];
    float* out = (float*)d_out;
    const int n = in_sizes[0] / 6;
    const int nchunks = (n + KC - 1) / KC;

    hipMemsetAsync(d_out, 0, NB2 * sizeof(float), stream);  // atomic target
    kde_mfma_kernel<<<NBLK, TPB, 0, stream>>>(x, ex, ey, out, n, nchunks);
    kde_final_kernel<<<1, TPB, 0, stream>>>(out, ex, ey);
}